// Round 2
// baseline (1992.187 us; speedup 1.0000x reference)
//
#include <hip/hip_runtime.h>

typedef __attribute__((ext_vector_type(8))) short short8;
typedef __attribute__((ext_vector_type(4))) float f32x4;

__device__ inline unsigned short f2bf(float f) {
    union { float f; unsigned int u; } v; v.f = f;
    unsigned int u = v.u;
    unsigned int r = (u + 0x7FFFu + ((u >> 16) & 1u)) >> 16;
    return (unsigned short)r;
}
__device__ inline float bf2f(unsigned short u) {
    union { unsigned int u; float f; } v; v.u = ((unsigned int)u) << 16;
    return v.f;
}
__device__ inline void unpack2(unsigned int p, float& a, float& b) {
    union { unsigned int u; float f; } va, vb;
    va.u = p << 16;
    vb.u = p & 0xFFFF0000u;
    a = va.f; b = vb.f;
}
__device__ inline unsigned int pack2(float a, float b) {
    return (unsigned int)f2bf(a) | ((unsigned int)f2bf(b) << 16);
}
__device__ inline float fast_tanh(float x) {
    x = fminf(fmaxf(x, -15.f), 15.f);
    float e = __expf(2.f * x);
    return (e - 1.f) / (e + 1.f);
}
__device__ __forceinline__ void gld_lds16(const void* g, void* l) {
    __builtin_amdgcn_global_load_lds(
        (const __attribute__((address_space(1))) unsigned int*)g,
        (__attribute__((address_space(3))) unsigned int*)l, 16, 0, 0);
}

// ---------------- weight fp32 -> bf16 conversion ----------------
__global__ void convert_weights(const float* __restrict__ Wt, const float* __restrict__ W1,
                                const float* __restrict__ W2, const float* __restrict__ W3,
                                unsigned short* __restrict__ dst) {
    int idx = blockIdx.x * 256 + threadIdx.x;
    float v;
    if (idx < 921600) v = Wt[idx];
    else if (idx < 921600 + 524288) v = W1[idx - 921600];
    else if (idx < 921600 + 524288 + 131072) v = W2[idx - 921600 - 524288];
    else v = W3[idx - 921600 - 524288 - 131072];
    dst[idx] = f2bf(v);
}

// ---------------- bulk fp32 -> bf16 (8 elems/thread) ----------------
__global__ void convert_f32_bf16(const float* __restrict__ src, unsigned short* __restrict__ dst, int n8) {
    int i = blockIdx.x * 256 + threadIdx.x;
    if (i >= n8) return;
    const float4* s = (const float4*)src + (size_t)i * 2;
    float4 a = s[0], b = s[1];
    uint4 o;
    o.x = pack2(a.x, a.y); o.y = pack2(a.z, a.w);
    o.z = pack2(b.x, b.y); o.w = pack2(b.z, b.w);
    ((uint4*)dst)[i] = o;
}

// ---------------- fast transfer GEMM: C[M,960] = A_bf[M,960] @ Wt_bf^T + bt ----------------
// BM=128 BN=192 BK=32, 256 threads (4 waves as 2m x 2n), wave tile 64x96.
// global_load_lds width-16 staging, unpadded LDS (m97 pattern).
// T1 XCD-bijective block swizzle (m204 formula): the 5 n-blocks sharing an
// A-tile land on one XCD -> A re-reads hit XCD-local L2.
__global__ __launch_bounds__(256, 3) void transfer_gemm_fast(
    const unsigned short* __restrict__ A, int M,
    const unsigned short* __restrict__ Wt_bf, const float* __restrict__ bt,
    unsigned short* __restrict__ out) {
    __shared__ unsigned short lA[128 * 32];   // 8 KB
    __shared__ unsigned short lB[192 * 32];   // 12 KB

    // --- XCD-bijective remap (bijective for any nwg, incl. nwg%8 != 0) ---
    const int nwg = gridDim.x * gridDim.y;
    const int orig = blockIdx.y * gridDim.x + blockIdx.x;
    const int qq = nwg >> 3, rr = nwg & 7;
    const int xcd = orig & 7, lo = orig >> 3;
    const int wgid = (xcd < rr ? xcd * (qq + 1) : rr * (qq + 1) + (xcd - rr) * qq) + lo;
    const int n0 = (wgid % gridDim.x) * 192;
    const int m0 = (wgid / gridDim.x) * 128;

    const int tid = threadIdx.x;
    const int wave = tid >> 6, lane = tid & 63;
    const int wm = wave & 1, wn = wave >> 1;
    const int q = lane >> 4, ra = lane & 15;

    // staging: 20 segments of 1024B (A:0..7, B:8..19); wave w owns segs w*5..w*5+4
    const int lr = lane >> 2;
    const int lc = (lane & 3) * 8;
    const unsigned short* srcs[5];
    unsigned short* dsts[5];
#pragma unroll
    for (int j = 0; j < 5; j++) {
        int s = wave * 5 + j;
        if (s < 8) {
            int gr = m0 + s * 16 + lr; if (gr > M - 1) gr = M - 1;
            srcs[j] = A + (size_t)gr * 960 + lc;
            dsts[j] = &lA[s * 512];
        } else {
            int gr = n0 + (s - 8) * 16 + lr;
            srcs[j] = Wt_bf + (size_t)gr * 960 + lc;
            dsts[j] = &lB[(s - 8) * 512];
        }
    }

    f32x4 acc[4][6];
#pragma unroll
    for (int i = 0; i < 4; i++)
#pragma unroll
        for (int j = 0; j < 6; j++) acc[i][j] = (f32x4)0.f;

    for (int k0 = 0; k0 < 960; k0 += 32) {
#pragma unroll
        for (int j = 0; j < 5; j++) gld_lds16(srcs[j] + k0, dsts[j]);
        __syncthreads();
        short8 af[4];
#pragma unroll
        for (int mt = 0; mt < 4; mt++)
            af[mt] = *(const short8*)&lA[(wm * 64 + mt * 16 + ra) * 32 + q * 8];
#pragma unroll
        for (int nt = 0; nt < 6; nt++) {
            short8 bfr = *(const short8*)&lB[(wn * 96 + nt * 16 + ra) * 32 + q * 8];
#pragma unroll
            for (int mt = 0; mt < 4; mt++)
                acc[mt][nt] = __builtin_amdgcn_mfma_f32_16x16x32_bf16(af[mt], bfr, acc[mt][nt], 0, 0, 0);
        }
        __syncthreads();
    }
#pragma unroll
    for (int nt = 0; nt < 6; nt++) {
        int n = n0 + wn * 96 + nt * 16 + ra;
        float bias = bt[n];
#pragma unroll
        for (int mt = 0; mt < 4; mt++) {
#pragma unroll
            for (int i = 0; i < 4; i++) {
                int m = m0 + wm * 64 + mt * 16 + q * 4 + i;
                if (m < M) out[(size_t)m * 960 + n] = f2bf(acc[mt][nt][i] + bias);
            }
        }
    }
}

// ---------------- fallback transfer GEMM (round-0, fp32 A inline convert) ----------------
#define TG_LDA 40
#define TG_LDB 40
__global__ __launch_bounds__(512, 2) void transfer_gemm_slow(
    const float* __restrict__ A, int M,
    const unsigned short* __restrict__ Wt_bf, const float* __restrict__ bt,
    unsigned short* __restrict__ out) {
    __shared__ unsigned short lA[128 * TG_LDA];
    __shared__ unsigned short lB[192 * TG_LDB];
    const int n0 = blockIdx.x * 192;
    const int m0 = blockIdx.y * 128;
    const int tid = threadIdx.x;
    const int wave = tid >> 6, lane = tid & 63;
    const int wm = wave & 1, wn = wave >> 1;
    const int q = lane >> 4, ra = lane & 15;

    f32x4 acc[4][3];
#pragma unroll
    for (int i = 0; i < 4; i++)
#pragma unroll
        for (int j = 0; j < 3; j++) acc[i][j] = (f32x4)0.f;

    for (int k0 = 0; k0 < 960; k0 += 32) {
#pragma unroll
        for (int i = 0; i < 2; i++) {
            int idx = tid + i * 512;
            int row = idx >> 3, c4 = idx & 7;
            float4 f;
            if (m0 + row < M) f = *((const float4*)(A + (size_t)(m0 + row) * 960 + k0) + c4);
            else f = make_float4(0.f, 0.f, 0.f, 0.f);
            unsigned int p0 = pack2(f.x, f.y), p1 = pack2(f.z, f.w);
            *(uint2*)&lA[row * TG_LDA + c4 * 4] = make_uint2(p0, p1);
        }
#pragma unroll
        for (int i = 0; i < 3; i++) {
            int idx = tid + i * 512;
            int row = idx >> 3, c4 = idx & 7;
            uint2 d = *(const uint2*)(Wt_bf + (size_t)(n0 + row) * 960 + k0 + c4 * 4);
            *(uint2*)&lB[row * TG_LDB + c4 * 4] = d;
        }
        __syncthreads();
        short8 af[4];
#pragma unroll
        for (int mt = 0; mt < 4; mt++)
            af[mt] = *(const short8*)&lA[(wm * 64 + mt * 16 + ra) * TG_LDA + q * 8];
#pragma unroll
        for (int nt = 0; nt < 3; nt++) {
            short8 bfr = *(const short8*)&lB[(wn * 48 + nt * 16 + ra) * TG_LDB + q * 8];
#pragma unroll
            for (int mt = 0; mt < 4; mt++)
                acc[mt][nt] = __builtin_amdgcn_mfma_f32_16x16x32_bf16(af[mt], bfr, acc[mt][nt], 0, 0, 0);
        }
        __syncthreads();
    }
#pragma unroll
    for (int nt = 0; nt < 3; nt++) {
        int n = n0 + wn * 48 + nt * 16 + ra;
        float bias = bt[n];
#pragma unroll
        for (int mt = 0; mt < 4; mt++) {
#pragma unroll
            for (int i = 0; i < 4; i++) {
                int m = m0 + wm * 64 + mt * 16 + q * 4 + i;
                if (m < M) out[(size_t)m * 960 + n] = f2bf(acc[mt][nt][i] + bias);
            }
        }
    }
}

// ---------------- fused gather + product + 4-layer MLP ----------------
// R1 change: 512 threads (8 waves), still 32 rows/block. LDS layouts and
// numerics identical to the 256-thread version; only work partitioning
// changed. LDS 51.2 KB -> 3 blocks/CU = 24 waves/CU (~75% occupancy) vs
// 10.5 before: the kernel was latency-bound (MfmaUtil 8.9, VALUBusy 14.8,
// HBM 10.5%, nothing saturated), so 2.3x wave count attacks the exposed
// barrier -> ds_read -> L2-weight-load -> MFMA chain directly.
#define FC_LD 72
#define H1_LD 520
#define H2_LD 264
#define H3_LD 136
__global__ __launch_bounds__(512, 6) void fused_mlp(
    const int* __restrict__ rows, const int* __restrict__ cols,
    const float* __restrict__ ux, const float* __restrict__ ixp,
    const unsigned short* __restrict__ TU, const unsigned short* __restrict__ TI,
    const unsigned short* __restrict__ W1b, const float* __restrict__ b1,
    const unsigned short* __restrict__ W2b, const float* __restrict__ b2,
    const unsigned short* __restrict__ W3b, const float* __restrict__ b3,
    const float* __restrict__ Wr, const float* __restrict__ br,
    float* __restrict__ out) {
    __shared__ int s_row[32], s_col[32];
    __shared__ unsigned short fc2[2][32 * FC_LD];   // also h2 after layer1
    __shared__ unsigned short h1[32 * H1_LD];       // also h3 after layer2
    unsigned short* h2 = &fc2[0][0];
    unsigned short* h3 = &h1[0];

    const int tid = threadIdx.x;
    const int wave = tid >> 6, lane = tid & 63;      // wave 0..7
    const int q = lane >> 4, ra = lane & 15;
    const int r0 = blockIdx.x * 32;
    if (tid < 32) { s_row[tid] = rows[r0 + tid]; s_col[tid] = cols[r0 + tid]; }
    __syncthreads();

    // gather mapping: 16 threads per row, 4 shorts (uint2) per thread per chunk
    const int srow = tid >> 4, g = tid & 15;
    const size_t tu_base = (size_t)s_row[srow] * 960;
    const size_t ti_base = (size_t)s_col[srow] * 960;

    // ---------- layer 1: factor[32,1024] @ W1^T -> h1[32,512], tanh ----------
    // 8 waves each own a 64-wide n-slice: acc[2 m][4 nt]
    f32x4 acc[2][4];
#pragma unroll
    for (int i = 0; i < 2; i++)
#pragma unroll
        for (int j = 0; j < 4; j++) acc[i][j] = (f32x4)0.f;

    // prologue: chunk 0 (indep features) packed; chunk 1 raw prefetch
    uint2 val0;
    {
        const float* src = (g < 8) ? (ux + (size_t)s_row[srow] * 32 + g * 4)
                                   : (ixp + (size_t)s_col[srow] * 32 + (g - 8) * 4);
        float4 f0 = ((const float4*)src)[0];
        val0.x = pack2(f0.x, f0.y); val0.y = pack2(f0.z, f0.w);
    }
    uint2 tu_r[2], ti_r[2];
    tu_r[1] = *(const uint2*)(TU + tu_base + g * 4);
    ti_r[1] = *(const uint2*)(TI + ti_base + g * 4);

#pragma unroll 2
    for (int kc = 0; kc < 16; kc++) {
        uint2 v;
        if (kc == 0) {
            v = val0;
        } else {
            uint2 tu8 = tu_r[kc & 1], ti8 = ti_r[kc & 1];
            float a0, a1, b0, b1f;
            unpack2(tu8.x, a0, a1); unpack2(ti8.x, b0, b1f); v.x = pack2(a0 * b0, a1 * b1f);
            unpack2(tu8.y, a0, a1); unpack2(ti8.y, b0, b1f); v.y = pack2(a0 * b0, a1 * b1f);
        }
        *(uint2*)&fc2[kc & 1][srow * FC_LD + g * 4] = v;
        __syncthreads();
        if (kc + 2 < 16) {   // prefetch raw gathers for chunk kc+2 (overlaps MFMA below)
            int j0 = (kc + 1) * 64 + g * 4;
            tu_r[kc & 1] = *(const uint2*)(TU + tu_base + j0);
            ti_r[kc & 1] = *(const uint2*)(TI + ti_base + j0);
        }
#pragma unroll
        for (int ks = 0; ks < 2; ks++) {
            short8 a0 = *(const short8*)&fc2[kc & 1][(ra)*FC_LD + ks * 32 + q * 8];
            short8 a1 = *(const short8*)&fc2[kc & 1][(16 + ra) * FC_LD + ks * 32 + q * 8];
            int kg = kc * 64 + ks * 32;
#pragma unroll
            for (int nt = 0; nt < 4; nt++) {
                int n = wave * 64 + nt * 16 + ra;
                short8 b = *(const short8*)(W1b + (size_t)n * 1024 + kg + q * 8);
                acc[0][nt] = __builtin_amdgcn_mfma_f32_16x16x32_bf16(a0, b, acc[0][nt], 0, 0, 0);
                acc[1][nt] = __builtin_amdgcn_mfma_f32_16x16x32_bf16(a1, b, acc[1][nt], 0, 0, 0);
            }
        }
    }
    __syncthreads();
#pragma unroll
    for (int nt = 0; nt < 4; nt++) {
        int n = wave * 64 + nt * 16 + ra;
        float bias = b1[n];
#pragma unroll
        for (int mt = 0; mt < 2; mt++)
#pragma unroll
            for (int i = 0; i < 4; i++) {
                int m = mt * 16 + q * 4 + i;
                h1[m * H1_LD + n] = f2bf(fast_tanh(acc[mt][nt][i] + bias));
            }
    }
    __syncthreads();

    // ---------- layer 2: h1[32,512] @ W2^T -> h2[32,256], tanh ----------
    // 8 waves each own a 32-wide n-slice: acc2[2][2]
    f32x4 acc2[2][2];
#pragma unroll
    for (int i = 0; i < 2; i++)
#pragma unroll
        for (int j = 0; j < 2; j++) acc2[i][j] = (f32x4)0.f;
    for (int k = 0; k < 512; k += 32) {
        short8 a0 = *(const short8*)&h1[(ra)*H1_LD + k + q * 8];
        short8 a1 = *(const short8*)&h1[(16 + ra) * H1_LD + k + q * 8];
#pragma unroll
        for (int nt = 0; nt < 2; nt++) {
            int n = wave * 32 + nt * 16 + ra;
            short8 b = *(const short8*)(W2b + (size_t)n * 512 + k + q * 8);
            acc2[0][nt] = __builtin_amdgcn_mfma_f32_16x16x32_bf16(a0, b, acc2[0][nt], 0, 0, 0);
            acc2[1][nt] = __builtin_amdgcn_mfma_f32_16x16x32_bf16(a1, b, acc2[1][nt], 0, 0, 0);
        }
    }
    __syncthreads();   // all h1 reads done before h2 (aliases fc2) writes are consumed next
#pragma unroll
    for (int nt = 0; nt < 2; nt++) {
        int n = wave * 32 + nt * 16 + ra;
        float bias = b2[n];
#pragma unroll
        for (int mt = 0; mt < 2; mt++)
#pragma unroll
            for (int i = 0; i < 4; i++) {
                int m = mt * 16 + q * 4 + i;
                h2[m * H2_LD + n] = f2bf(fast_tanh(acc2[mt][nt][i] + bias));
            }
    }
    __syncthreads();

    // ---------- layer 3: h2[32,256] @ W3^T -> h3[32,128], tanh ----------
    // 8 waves each own a 16-wide n-slice: acc3[2]
    f32x4 acc3[2];
    acc3[0] = (f32x4)0.f; acc3[1] = (f32x4)0.f;
    for (int k = 0; k < 256; k += 32) {
        short8 a0 = *(const short8*)&h2[(ra)*H2_LD + k + q * 8];
        short8 a1 = *(const short8*)&h2[(16 + ra) * H2_LD + k + q * 8];
        int n = wave * 16 + ra;
        short8 b = *(const short8*)(W3b + (size_t)n * 256 + k + q * 8);
        acc3[0] = __builtin_amdgcn_mfma_f32_16x16x32_bf16(a0, b, acc3[0], 0, 0, 0);
        acc3[1] = __builtin_amdgcn_mfma_f32_16x16x32_bf16(a1, b, acc3[1], 0, 0, 0);
    }
    __syncthreads();   // h2 reads done before h3 (aliases h1) writes are consumed
    {
        int n = wave * 16 + ra;
        float bias = b3[n];
#pragma unroll
        for (int mt = 0; mt < 2; mt++)
#pragma unroll
            for (int i = 0; i < 4; i++) {
                int m = mt * 16 + q * 4 + i;
                h3[m * H3_LD + n] = f2bf(fast_tanh(acc3[mt][i] + bias));
            }
    }
    __syncthreads();

    // ---------- output: h3[32,128] . Wr + br + 3.5 ----------
    {
        int row = tid >> 4, seg = tid & 15;
        float s = 0.f;
#pragma unroll
        for (int i = 0; i < 8; i++) {
            int k = seg * 8 + i;
            s += bf2f(h3[row * H3_LD + k]) * Wr[k];
        }
        s += __shfl_xor(s, 1);
        s += __shfl_xor(s, 2);
        s += __shfl_xor(s, 4);
        s += __shfl_xor(s, 8);
        if (seg == 0) out[r0 + row] = s + br[0] + 3.5f;
    }
}

extern "C" void kernel_launch(void* const* d_in, const int* in_sizes, int n_in,
                              void* d_out, int out_size, void* d_ws, size_t ws_size,
                              hipStream_t stream) {
    const int* rows = (const int*)d_in[0];
    const int* cols = (const int*)d_in[1];
    const float* user_inter = (const float*)d_in[2];
    const float* item_inter = (const float*)d_in[3];
    const float* ux = (const float*)d_in[4];
    const float* ixp = (const float*)d_in[5];
    const float* Wt = (const float*)d_in[6];
    const float* bt = (const float*)d_in[7];
    const float* W1 = (const float*)d_in[8];
    const float* b1 = (const float*)d_in[9];
    const float* W2 = (const float*)d_in[10];
    const float* b2 = (const float*)d_in[11];
    const float* W3 = (const float*)d_in[12];
    const float* b3 = (const float*)d_in[13];
    const float* Wr = (const float*)d_in[14];
    const float* br = (const float*)d_in[15];

    unsigned short* ws = (unsigned short*)d_ws;
    unsigned short* TU = ws;                      // 96,000,000 shorts
    unsigned short* TI = ws + 96000000ull;        // 48,000,000 shorts

    const bool fast = (ws_size >= 483219456ull);

    if (fast) {
        unsigned short* Abf = ws + 144000000ull;       // 96,000,000 shorts (shared stage)
        unsigned short* Wt_bf = ws + 240000000ull;
        unsigned short* W1_bf = Wt_bf + 921600;
        unsigned short* W2_bf = W1_bf + 524288;
        unsigned short* W3_bf = W2_bf + 131072;

        convert_weights<<<6288, 256, 0, stream>>>(Wt, W1, W2, W3, Wt_bf);
        // item first (smaller), then user reuses the same staging region
        convert_f32_bf16<<<23438, 256, 0, stream>>>(item_inter, Abf, 6000000);
        transfer_gemm_fast<<<dim3(5, 391), 256, 0, stream>>>(Abf, 50000, Wt_bf, bt, TI);
        convert_f32_bf16<<<46875, 256, 0, stream>>>(user_inter, Abf, 12000000);
        transfer_gemm_fast<<<dim3(5, 782), 256, 0, stream>>>(Abf, 100000, Wt_bf, bt, TU);
        fused_mlp<<<4096, 512, 0, stream>>>(rows, cols, ux, ixp, TU, TI,
                                            W1_bf, b1, W2_bf, b2, W3_bf, b3, Wr, br,
                                            (float*)d_out);
    } else {
        unsigned short* Wt_bf = ws + 144000000ull;
        unsigned short* W1_bf = Wt_bf + 921600;
        unsigned short* W2_bf = W1_bf + 524288;
        unsigned short* W3_bf = W2_bf + 131072;

        convert_weights<<<6288, 256, 0, stream>>>(Wt, W1, W2, W3, Wt_bf);
        transfer_gemm_slow<<<dim3(5, 782), 512, 0, stream>>>(user_inter, 100000, Wt_bf, bt, TU);
        transfer_gemm_slow<<<dim3(5, 391), 512, 0, stream>>>(item_inter, 50000, Wt_bf, bt, TI);
        fused_mlp<<<4096, 512, 0, stream>>>(rows, cols, ux, ixp, TU, TI,
                                            W1_bf, b1, W2_bf, b2, W3_bf, b3, Wr, br,
                                            (float*)d_out);
    }
}

// Round 3
// 1862.631 us; speedup vs baseline: 1.0696x; 1.0696x over previous
//
#include <hip/hip_runtime.h>

typedef __attribute__((ext_vector_type(8))) short short8;
typedef __attribute__((ext_vector_type(4))) float f32x4;

__device__ inline unsigned short f2bf(float f) {
    union { float f; unsigned int u; } v; v.f = f;
    unsigned int u = v.u;
    unsigned int r = (u + 0x7FFFu + ((u >> 16) & 1u)) >> 16;
    return (unsigned short)r;
}
__device__ inline float bf2f(unsigned short u) {
    union { unsigned int u; float f; } v; v.u = ((unsigned int)u) << 16;
    return v.f;
}
__device__ inline void unpack2(unsigned int p, float& a, float& b) {
    union { unsigned int u; float f; } va, vb;
    va.u = p << 16;
    vb.u = p & 0xFFFF0000u;
    a = va.f; b = vb.f;
}
__device__ inline unsigned int pack2(float a, float b) {
    return (unsigned int)f2bf(a) | ((unsigned int)f2bf(b) << 16);
}
__device__ inline float fast_tanh(float x) {
    x = fminf(fmaxf(x, -15.f), 15.f);
    float e = __expf(2.f * x);
    return (e - 1.f) / (e + 1.f);
}
__device__ __forceinline__ void gld_lds16(const void* g, void* l) {
    __builtin_amdgcn_global_load_lds(
        (const __attribute__((address_space(1))) unsigned int*)g,
        (__attribute__((address_space(3))) unsigned int*)l, 16, 0, 0);
}

// ---------------- weight fp32 -> bf16 conversion ----------------
__global__ void convert_weights(const float* __restrict__ Wt, const float* __restrict__ W1,
                                const float* __restrict__ W2, const float* __restrict__ W3,
                                unsigned short* __restrict__ dst) {
    int idx = blockIdx.x * 256 + threadIdx.x;
    float v;
    if (idx < 921600) v = Wt[idx];
    else if (idx < 921600 + 524288) v = W1[idx - 921600];
    else if (idx < 921600 + 524288 + 131072) v = W2[idx - 921600 - 524288];
    else v = W3[idx - 921600 - 524288 - 131072];
    dst[idx] = f2bf(v);
}

// ---------------- bulk fp32 -> bf16 (8 elems/thread) ----------------
__global__ void convert_f32_bf16(const float* __restrict__ src, unsigned short* __restrict__ dst, int n8) {
    int i = blockIdx.x * 256 + threadIdx.x;
    if (i >= n8) return;
    const float4* s = (const float4*)src + (size_t)i * 2;
    float4 a = s[0], b = s[1];
    uint4 o;
    o.x = pack2(a.x, a.y); o.y = pack2(a.z, a.w);
    o.z = pack2(b.x, b.y); o.w = pack2(b.z, b.w);
    ((uint4*)dst)[i] = o;
}

// ---------------- fast transfer GEMM: C[M,960] = A_bf[M,960] @ Wt_bf^T + bt ----------------
// BM=128 BN=192 BK=32, 256 threads (4 waves as 2m x 2n), wave tile 64x96.
// global_load_lds width-16 staging, unpadded LDS (m97 pattern).
// T1 XCD-bijective block swizzle (m204 formula).
__global__ __launch_bounds__(256, 3) void transfer_gemm_fast(
    const unsigned short* __restrict__ A, int M,
    const unsigned short* __restrict__ Wt_bf, const float* __restrict__ bt,
    unsigned short* __restrict__ out) {
    __shared__ unsigned short lA[128 * 32];   // 8 KB
    __shared__ unsigned short lB[192 * 32];   // 12 KB

    // --- XCD-bijective remap (bijective for any nwg, incl. nwg%8 != 0) ---
    const int nwg = gridDim.x * gridDim.y;
    const int orig = blockIdx.y * gridDim.x + blockIdx.x;
    const int qq = nwg >> 3, rr = nwg & 7;
    const int xcd = orig & 7, lo = orig >> 3;
    const int wgid = (xcd < rr ? xcd * (qq + 1) : rr * (qq + 1) + (xcd - rr) * qq) + lo;
    const int n0 = (wgid % gridDim.x) * 192;
    const int m0 = (wgid / gridDim.x) * 128;

    const int tid = threadIdx.x;
    const int wave = tid >> 6, lane = tid & 63;
    const int wm = wave & 1, wn = wave >> 1;
    const int q = lane >> 4, ra = lane & 15;

    // staging: 20 segments of 1024B (A:0..7, B:8..19); wave w owns segs w*5..w*5+4
    const int lr = lane >> 2;
    const int lc = (lane & 3) * 8;
    const unsigned short* srcs[5];
    unsigned short* dsts[5];
#pragma unroll
    for (int j = 0; j < 5; j++) {
        int s = wave * 5 + j;
        if (s < 8) {
            int gr = m0 + s * 16 + lr; if (gr > M - 1) gr = M - 1;
            srcs[j] = A + (size_t)gr * 960 + lc;
            dsts[j] = &lA[s * 512];
        } else {
            int gr = n0 + (s - 8) * 16 + lr;
            srcs[j] = Wt_bf + (size_t)gr * 960 + lc;
            dsts[j] = &lB[(s - 8) * 512];
        }
    }

    f32x4 acc[4][6];
#pragma unroll
    for (int i = 0; i < 4; i++)
#pragma unroll
        for (int j = 0; j < 6; j++) acc[i][j] = (f32x4)0.f;

    for (int k0 = 0; k0 < 960; k0 += 32) {
#pragma unroll
        for (int j = 0; j < 5; j++) gld_lds16(srcs[j] + k0, dsts[j]);
        __syncthreads();
        short8 af[4];
#pragma unroll
        for (int mt = 0; mt < 4; mt++)
            af[mt] = *(const short8*)&lA[(wm * 64 + mt * 16 + ra) * 32 + q * 8];
#pragma unroll
        for (int nt = 0; nt < 6; nt++) {
            short8 bfr = *(const short8*)&lB[(wn * 96 + nt * 16 + ra) * 32 + q * 8];
#pragma unroll
            for (int mt = 0; mt < 4; mt++)
                acc[mt][nt] = __builtin_amdgcn_mfma_f32_16x16x32_bf16(af[mt], bfr, acc[mt][nt], 0, 0, 0);
        }
        __syncthreads();
    }
#pragma unroll
    for (int nt = 0; nt < 6; nt++) {
        int n = n0 + wn * 96 + nt * 16 + ra;
        float bias = bt[n];
#pragma unroll
        for (int mt = 0; mt < 4; mt++) {
#pragma unroll
            for (int i = 0; i < 4; i++) {
                int m = m0 + wm * 64 + mt * 16 + q * 4 + i;
                if (m < M) out[(size_t)m * 960 + n] = f2bf(acc[mt][nt][i] + bias);
            }
        }
    }
}

// ---------------- fallback transfer GEMM (round-0, fp32 A inline convert) ----------------
#define TG_LDA 40
#define TG_LDB 40
__global__ __launch_bounds__(512, 2) void transfer_gemm_slow(
    const float* __restrict__ A, int M,
    const unsigned short* __restrict__ Wt_bf, const float* __restrict__ bt,
    unsigned short* __restrict__ out) {
    __shared__ unsigned short lA[128 * TG_LDA];
    __shared__ unsigned short lB[192 * TG_LDB];
    const int n0 = blockIdx.x * 192;
    const int m0 = blockIdx.y * 128;
    const int tid = threadIdx.x;
    const int wave = tid >> 6, lane = tid & 63;
    const int wm = wave & 1, wn = wave >> 1;
    const int q = lane >> 4, ra = lane & 15;

    f32x4 acc[4][3];
#pragma unroll
    for (int i = 0; i < 4; i++)
#pragma unroll
        for (int j = 0; j < 3; j++) acc[i][j] = (f32x4)0.f;

    for (int k0 = 0; k0 < 960; k0 += 32) {
#pragma unroll
        for (int i = 0; i < 2; i++) {
            int idx = tid + i * 512;
            int row = idx >> 3, c4 = idx & 7;
            float4 f;
            if (m0 + row < M) f = *((const float4*)(A + (size_t)(m0 + row) * 960 + k0) + c4);
            else f = make_float4(0.f, 0.f, 0.f, 0.f);
            unsigned int p0 = pack2(f.x, f.y), p1 = pack2(f.z, f.w);
            *(uint2*)&lA[row * TG_LDA + c4 * 4] = make_uint2(p0, p1);
        }
#pragma unroll
        for (int i = 0; i < 3; i++) {
            int idx = tid + i * 512;
            int row = idx >> 3, c4 = idx & 7;
            uint2 d = *(const uint2*)(Wt_bf + (size_t)(n0 + row) * 960 + k0 + c4 * 4);
            *(uint2*)&lB[row * TG_LDB + c4 * 4] = d;
        }
        __syncthreads();
        short8 af[4];
#pragma unroll
        for (int mt = 0; mt < 4; mt++)
            af[mt] = *(const short8*)&lA[(wm * 64 + mt * 16 + ra) * TG_LDA + q * 8];
#pragma unroll
        for (int nt = 0; nt < 3; nt++) {
            short8 bfr = *(const short8*)&lB[(wn * 48 + nt * 16 + ra) * TG_LDB + q * 8];
#pragma unroll
            for (int mt = 0; mt < 4; mt++)
                acc[mt][nt] = __builtin_amdgcn_mfma_f32_16x16x32_bf16(af[mt], bfr, acc[mt][nt], 0, 0, 0);
        }
        __syncthreads();
    }
#pragma unroll
    for (int nt = 0; nt < 3; nt++) {
        int n = n0 + wn * 48 + nt * 16 + ra;
        float bias = bt[n];
#pragma unroll
        for (int mt = 0; mt < 4; mt++) {
#pragma unroll
            for (int i = 0; i < 4; i++) {
                int m = m0 + wm * 64 + mt * 16 + q * 4 + i;
                if (m < M) out[(size_t)m * 960 + n] = f2bf(acc[mt][nt][i] + bias);
            }
        }
    }
}

// ---------------- fused gather + product + 4-layer MLP ----------------
// R2 change: kill the per-block serial gather chain. R1/R2 showed the kernel
// latency-bound with occupancy NOT the lever (33% -> 68% occupancy, dur flat):
// the layer-1 loop prefetched gathers only 1 chunk (~350 cyc) ahead of a
// ~900-cyc HBM latency, and the per-chunk barrier made all waves wait on the
// block's slowest gather -> 15 serial exposed waits per block. Now ALL 30
// gather uint2s stream through registers with a 5-chunk-deep pipeline
// (~2000 cyc cover); the chunk loop has zero exposed global latency.
// Fully unrolled -> all reg-array indices static (no scratch).
#define FC_LD 72
#define H1_LD 520
#define H2_LD 264
#define H3_LD 136
__global__ __launch_bounds__(512, 4) void fused_mlp(
    const int* __restrict__ rows, const int* __restrict__ cols,
    const float* __restrict__ ux, const float* __restrict__ ixp,
    const unsigned short* __restrict__ TU, const unsigned short* __restrict__ TI,
    const unsigned short* __restrict__ W1b, const float* __restrict__ b1,
    const unsigned short* __restrict__ W2b, const float* __restrict__ b2,
    const unsigned short* __restrict__ W3b, const float* __restrict__ b3,
    const float* __restrict__ Wr, const float* __restrict__ br,
    float* __restrict__ out) {
    __shared__ int s_row[32], s_col[32];
    __shared__ unsigned short fc2[2][32 * FC_LD];   // also h2 after layer1
    __shared__ unsigned short h1[32 * H1_LD];       // also h3 after layer2
    unsigned short* h2 = &fc2[0][0];
    unsigned short* h3 = &h1[0];

    const int tid = threadIdx.x;
    const int wave = tid >> 6, lane = tid & 63;      // wave 0..7
    const int q = lane >> 4, ra = lane & 15;
    const int r0 = blockIdx.x * 32;
    if (tid < 32) { s_row[tid] = rows[r0 + tid]; s_col[tid] = cols[r0 + tid]; }
    __syncthreads();

    // gather mapping: 16 threads per row, 4 shorts (uint2) per thread per chunk
    const int srow = tid >> 4, g = tid & 15;
    const size_t tu_base = (size_t)s_row[srow] * 960;
    const size_t ti_base = (size_t)s_col[srow] * 960;

    // ---------- layer 1: factor[32,1024] @ W1^T -> h1[32,512], tanh ----------
    f32x4 acc[2][4];
#pragma unroll
    for (int i = 0; i < 2; i++)
#pragma unroll
        for (int j = 0; j < 4; j++) acc[i][j] = (f32x4)0.f;

    // chunk 0 (indep features) packed up front
    uint2 val0;
    {
        const float* src = (g < 8) ? (ux + (size_t)s_row[srow] * 32 + g * 4)
                                   : (ixp + (size_t)s_col[srow] * 32 + (g - 8) * 4);
        float4 f0 = ((const float4*)src)[0];
        val0.x = pack2(f0.x, f0.y); val0.y = pack2(f0.z, f0.w);
    }
    // register-streamed gathers: 15 uint2 pairs, pipeline depth 5 chunks
    uint2 tu_r[15], ti_r[15];
#pragma unroll
    for (int j = 0; j < 5; j++) {
        tu_r[j] = *(const uint2*)(TU + tu_base + j * 64 + g * 4);
        ti_r[j] = *(const uint2*)(TI + ti_base + j * 64 + g * 4);
    }

#pragma unroll
    for (int kc = 0; kc < 16; kc++) {
        uint2 v;
        if (kc == 0) {
            v = val0;
        } else {
            uint2 tu8 = tu_r[kc - 1], ti8 = ti_r[kc - 1];
            float a0f, a1f, b0f, b1f;
            unpack2(tu8.x, a0f, a1f); unpack2(ti8.x, b0f, b1f); v.x = pack2(a0f * b0f, a1f * b1f);
            unpack2(tu8.y, a0f, a1f); unpack2(ti8.y, b0f, b1f); v.y = pack2(a0f * b0f, a1f * b1f);
        }
        *(uint2*)&fc2[kc & 1][srow * FC_LD + g * 4] = v;
        __syncthreads();
        if (kc < 10) {   // keep the gather stream 5 chunks ahead of use
            int j = kc + 5;
            tu_r[j] = *(const uint2*)(TU + tu_base + j * 64 + g * 4);
            ti_r[j] = *(const uint2*)(TI + ti_base + j * 64 + g * 4);
        }
#pragma unroll
        for (int ks = 0; ks < 2; ks++) {
            short8 a0 = *(const short8*)&fc2[kc & 1][(ra)*FC_LD + ks * 32 + q * 8];
            short8 a1 = *(const short8*)&fc2[kc & 1][(16 + ra) * FC_LD + ks * 32 + q * 8];
            int kg = kc * 64 + ks * 32;
#pragma unroll
            for (int nt = 0; nt < 4; nt++) {
                int n = wave * 64 + nt * 16 + ra;
                short8 b = *(const short8*)(W1b + (size_t)n * 1024 + kg + q * 8);
                acc[0][nt] = __builtin_amdgcn_mfma_f32_16x16x32_bf16(a0, b, acc[0][nt], 0, 0, 0);
                acc[1][nt] = __builtin_amdgcn_mfma_f32_16x16x32_bf16(a1, b, acc[1][nt], 0, 0, 0);
            }
        }
    }
    __syncthreads();
#pragma unroll
    for (int nt = 0; nt < 4; nt++) {
        int n = wave * 64 + nt * 16 + ra;
        float bias = b1[n];
#pragma unroll
        for (int mt = 0; mt < 2; mt++)
#pragma unroll
            for (int i = 0; i < 4; i++) {
                int m = mt * 16 + q * 4 + i;
                h1[m * H1_LD + n] = f2bf(fast_tanh(acc[mt][nt][i] + bias));
            }
    }
    __syncthreads();

    // ---------- layer 2: h1[32,512] @ W2^T -> h2[32,256], tanh ----------
    f32x4 acc2[2][2];
#pragma unroll
    for (int i = 0; i < 2; i++)
#pragma unroll
        for (int j = 0; j < 2; j++) acc2[i][j] = (f32x4)0.f;
    for (int k = 0; k < 512; k += 32) {
        short8 a0 = *(const short8*)&h1[(ra)*H1_LD + k + q * 8];
        short8 a1 = *(const short8*)&h1[(16 + ra) * H1_LD + k + q * 8];
#pragma unroll
        for (int nt = 0; nt < 2; nt++) {
            int n = wave * 32 + nt * 16 + ra;
            short8 b = *(const short8*)(W2b + (size_t)n * 512 + k + q * 8);
            acc2[0][nt] = __builtin_amdgcn_mfma_f32_16x16x32_bf16(a0, b, acc2[0][nt], 0, 0, 0);
            acc2[1][nt] = __builtin_amdgcn_mfma_f32_16x16x32_bf16(a1, b, acc2[1][nt], 0, 0, 0);
        }
    }
    __syncthreads();   // all h1 reads done before h2 (aliases fc2) writes are consumed next
#pragma unroll
    for (int nt = 0; nt < 2; nt++) {
        int n = wave * 32 + nt * 16 + ra;
        float bias = b2[n];
#pragma unroll
        for (int mt = 0; mt < 2; mt++)
#pragma unroll
            for (int i = 0; i < 4; i++) {
                int m = mt * 16 + q * 4 + i;
                h2[m * H2_LD + n] = f2bf(fast_tanh(acc2[mt][nt][i] + bias));
            }
    }
    __syncthreads();

    // ---------- layer 3: h2[32,256] @ W3^T -> h3[32,128], tanh ----------
    f32x4 acc3[2];
    acc3[0] = (f32x4)0.f; acc3[1] = (f32x4)0.f;
    for (int k = 0; k < 256; k += 32) {
        short8 a0 = *(const short8*)&h2[(ra)*H2_LD + k + q * 8];
        short8 a1 = *(const short8*)&h2[(16 + ra) * H2_LD + k + q * 8];
        int n = wave * 16 + ra;
        short8 b = *(const short8*)(W3b + (size_t)n * 256 + k + q * 8);
        acc3[0] = __builtin_amdgcn_mfma_f32_16x16x32_bf16(a0, b, acc3[0], 0, 0, 0);
        acc3[1] = __builtin_amdgcn_mfma_f32_16x16x32_bf16(a1, b, acc3[1], 0, 0, 0);
    }
    __syncthreads();   // h2 reads done before h3 (aliases h1) writes are consumed
    {
        int n = wave * 16 + ra;
        float bias = b3[n];
#pragma unroll
        for (int mt = 0; mt < 2; mt++)
#pragma unroll
            for (int i = 0; i < 4; i++) {
                int m = mt * 16 + q * 4 + i;
                h3[m * H3_LD + n] = f2bf(fast_tanh(acc3[mt][i] + bias));
            }
    }
    __syncthreads();

    // ---------- output: h3[32,128] . Wr + br + 3.5 ----------
    {
        int row = tid >> 4, seg = tid & 15;
        float s = 0.f;
#pragma unroll
        for (int i = 0; i < 8; i++) {
            int k = seg * 8 + i;
            s += bf2f(h3[row * H3_LD + k]) * Wr[k];
        }
        s += __shfl_xor(s, 1);
        s += __shfl_xor(s, 2);
        s += __shfl_xor(s, 4);
        s += __shfl_xor(s, 8);
        if (seg == 0) out[r0 + row] = s + br[0] + 3.5f;
    }
}

extern "C" void kernel_launch(void* const* d_in, const int* in_sizes, int n_in,
                              void* d_out, int out_size, void* d_ws, size_t ws_size,
                              hipStream_t stream) {
    const int* rows = (const int*)d_in[0];
    const int* cols = (const int*)d_in[1];
    const float* user_inter = (const float*)d_in[2];
    const float* item_inter = (const float*)d_in[3];
    const float* ux = (const float*)d_in[4];
    const float* ixp = (const float*)d_in[5];
    const float* Wt = (const float*)d_in[6];
    const float* bt = (const float*)d_in[7];
    const float* W1 = (const float*)d_in[8];
    const float* b1 = (const float*)d_in[9];
    const float* W2 = (const float*)d_in[10];
    const float* b2 = (const float*)d_in[11];
    const float* W3 = (const float*)d_in[12];
    const float* b3 = (const float*)d_in[13];
    const float* Wr = (const float*)d_in[14];
    const float* br = (const float*)d_in[15];

    unsigned short* ws = (unsigned short*)d_ws;
    unsigned short* TU = ws;                      // 96,000,000 shorts
    unsigned short* TI = ws + 96000000ull;        // 48,000,000 shorts

    const bool fast = (ws_size >= 483219456ull);

    if (fast) {
        unsigned short* Abf = ws + 144000000ull;       // 96,000,000 shorts (shared stage)
        unsigned short* Wt_bf = ws + 240000000ull;
        unsigned short* W1_bf = Wt_bf + 921600;
        unsigned short* W2_bf = W1_bf + 524288;
        unsigned short* W3_bf = W2_bf + 131072;

        convert_weights<<<6288, 256, 0, stream>>>(Wt, W1, W2, W3, Wt_bf);
        // item first (smaller), then user reuses the same staging region
        convert_f32_bf16<<<23438, 256, 0, stream>>>(item_inter, Abf, 6000000);
        transfer_gemm_fast<<<dim3(5, 391), 256, 0, stream>>>(Abf, 50000, Wt_bf, bt, TI);
        convert_f32_bf16<<<46875, 256, 0, stream>>>(user_inter, Abf, 12000000);
        transfer_gemm_fast<<<dim3(5, 782), 256, 0, stream>>>(Abf, 100000, Wt_bf, bt, TU);
        fused_mlp<<<4096, 512, 0, stream>>>(rows, cols, ux, ixp, TU, TI,
                                            W1_bf, b1, W2_bf, b2, W3_bf, b3, Wr, br,
                                            (float*)d_out);
    } else {
        unsigned short* Wt_bf = ws + 144000000ull;
        unsigned short* W1_bf = Wt_bf + 921600;
        unsigned short* W2_bf = W1_bf + 524288;
        unsigned short* W3_bf = W2_bf + 131072;

        convert_weights<<<6288, 256, 0, stream>>>(Wt, W1, W2, W3, Wt_bf);
        transfer_gemm_slow<<<dim3(5, 782), 512, 0, stream>>>(user_inter, 100000, Wt_bf, bt, TU);
        transfer_gemm_slow<<<dim3(5, 391), 512, 0, stream>>>(item_inter, 50000, Wt_bf, bt, TI);
        fused_mlp<<<4096, 512, 0, stream>>>(rows, cols, ux, ixp, TU, TI,
                                            W1_bf, b1, W2_bf, b2, W3_bf, b3, Wr, br,
                                            (float*)d_out);
    }
}